// Round 18
// baseline (215.241 us; speedup 1.0000x reference)
//
#include <hip/hip_runtime.h>
#include <stdint.h>

#define K_SEL 5000
#define NQ    262144   // 512*512
#define NB    2

// ---------------- ws layout (bytes) ----------------
#define BIAS_OFF 38912
#define W4_OFF   39424
#define ST_OFF   40960
#define XT_OFF   135168                      // channels-last f16 buffer (clear of st)
#define XT_BYTES ((size_t)NB * NQ * 40 * 2)  // 41,943,040
#define WS_NEED  (XT_OFF + XT_BYTES)

// ---------------- topk state (uint32 word offsets within st) ----------------
// [4..5] T  [6..7] need
// hist: r0 @16 (2x2048), r1 @4112 (2x2048), r2 @8208 (2x1024)
// [12304..22303] selList 2x5000 ; [22528..23551] per-block packed counts sel|(eq<<16)
#define WS_SEL   12304
#define WS_BCNT  22528

typedef _Float16 f16x8 __attribute__((ext_vector_type(8)));
typedef _Float16 f16x4 __attribute__((ext_vector_type(4)));
typedef float    f32x4 __attribute__((ext_vector_type(4)));
#define MFMA16(a,b,c) __builtin_amdgcn_mfma_f32_16x16x32_f16(a,b,c,0,0,0)

__device__ __forceinline__ const uint32_t* hist_base(const uint32_t* st, int r, int b) {
    return st + ((r == 0) ? (16 + b * 2048) : (r == 1) ? (16 + 4096 + b * 2048)
                                                       : (16 + 8192 + b * 1024));
}
__device__ __forceinline__ uint32_t* hist_base(uint32_t* st, int r, int b) {
    return st + ((r == 0) ? (16 + b * 2048) : (r == 1) ? (16 + 4096 + b * 2048)
                                                       : (16 + 8192 + b * 1024));
}

// ================= prep work (device fn): fold BN, pack MFMA fragments =================
__device__ void prep_work(int bid,
                          const float* __restrict__ w1, const float* __restrict__ g1,
                          const float* __restrict__ b1, const float* __restrict__ m1,
                          const float* __restrict__ v1,
                          const float* __restrict__ w2, const float* __restrict__ g2,
                          const float* __restrict__ b2, const float* __restrict__ m2,
                          const float* __restrict__ v2,
                          const float* __restrict__ w3, const float* __restrict__ g3,
                          const float* __restrict__ b3, const float* __restrict__ m3,
                          const float* __restrict__ v3,
                          const float* __restrict__ w4, const float* __restrict__ b4,
                          char* __restrict__ ws) {
    _Float16* wf = (_Float16*)ws;
    float* bias = (float*)(ws + BIAS_OFF);
    float* w4r  = (float*)(ws + W4_OFF);
    int tid = threadIdx.x;
    for (int t = bid * 256 + tid; t < 38 * 512; t += 64 * 256) {
        int frag = t >> 9, li = (t >> 3) & 63, j = t & 7;
        int lo = li & 15, hi = li >> 4;
        float val = 0.f;
        if (frag < 18) {                                  // conv1
            int ky = frag / 6, r = frag % 6, kx = r >> 1, mt = r & 1;
            int oc = mt * 16 + lo, ci = hi * 8 + j;
            if (oc < 24) val = w1[((oc * 33 + ci) * 3 + ky) * 3 + kx] * g1[oc] * rsqrtf(v1[oc] + 1e-5f);
        } else if (frag < 27) {                           // conv2: k = kx*24 + ci  (k<72)
            int f = frag - 18, ky = f / 3, kt = f % 3;
            int oc = lo, k = kt * 32 + hi * 8 + j;
            if (k < 72) {
                int kx = k / 24, ci = k % 24;
                val = w2[((oc * 24 + ci) * 3 + ky) * 3 + kx] * g2[oc] * rsqrtf(v2[oc] + 1e-5f);
            }
        } else if (frag < 36) {                           // conv3
            int s = frag - 27, ky = s / 3, kx = s % 3;
            int oc = lo, ci = hi * 8 + j;
            if (oc < 12 && ci < 16) val = w3[((oc * 16 + ci) * 3 + ky) * 3 + kx] * g3[oc] * rsqrtf(v3[oc] + 1e-5f);
        } else {                                          // conv1 pha channel
            int mt = frag - 36, oc = mt * 16 + lo, tap = hi * 8 + j;
            if (oc < 24 && tap < 9)
                val = w1[((oc * 33 + 32) * 3 + tap / 3) * 3 + tap % 3] * g1[oc] * rsqrtf(v1[oc] + 1e-5f);
        }
        wf[t] = (_Float16)val;
    }
    if (bid == 0) {
        if (tid < 53) {
            float v;
            if (tid < 24)      { float sc = g1[tid] * rsqrtf(v1[tid] + 1e-5f); v = b1[tid] - m1[tid] * sc; }
            else if (tid < 40) { int c = tid - 24; float sc = g2[c] * rsqrtf(v2[c] + 1e-5f); v = b2[c] - m2[c] * sc; }
            else if (tid < 52) { int c = tid - 40; float sc = g3[c] * rsqrtf(v3[c] + 1e-5f); v = b3[c] - m3[c] * sc; }
            else v = b4[0];
            bias[tid] = v;
        }
        if (tid < 144) { int t9 = tid / 16, ci = tid % 16; w4r[tid] = (ci < 12) ? w4[ci * 9 + t9] : 0.f; }
    }
}

// ================= wave-level chained radix scan (11/11/10-bit digits) =================
__device__ __forceinline__ void chain_scan(const uint32_t* __restrict__ st, int b, int nrounds,
                                           uint32_t* pref_out, uint32_t* rem_out) {
    int lane = threadIdx.x & 63;
    uint32_t pref = 0u, rem = K_SEL;
    for (int r = 0; r < nrounds; r++) {
        int nb = (r < 2) ? 11 : 10;
        int shift = (r == 0) ? 21 : (r == 1) ? 10 : 0;
        int per = (1 << nb) >> 6;
        const uint32_t* hist = hist_base(st, r, b);
        int topbin = (1 << nb) - 1 - lane * per;
        uint32_t p = 0;
        for (int q = 0; q < per; q++) p += hist[topbin - q];
        uint32_t cum = p;
        for (int o = 1; o < 64; o <<= 1) {
            uint32_t n = __shfl_up(cum, o);
            if (lane >= o) cum += n;
        }
        unsigned long long bal = __ballot(cum >= rem);
        int first = __ffsll(bal) - 1;
        uint32_t acc = cum - p;
        int ch = topbin;
        for (int q = 0; q < per; q++) {
            uint32_t h = hist[topbin - q];
            if (acc + h >= rem) { ch = topbin - q; break; }
            acc += h;
        }
        uint32_t chosen = (uint32_t)__shfl(ch, first);
        uint32_t nrem   = (uint32_t)__shfl((int)(rem - acc), first);
        pref |= chosen << shift;
        rem = nrem;
    }
    *pref_out = pref;
    *rem_out = rem;
}

// ================= tu work: channels-last transpose (tb<2048) / 4x upsample =================
__device__ __forceinline__ void tu_work(int tb, const float* __restrict__ hid,
                                        const float* __restrict__ pha,
                                        _Float16* __restrict__ xt,
                                        float* __restrict__ out) {
    int tid = threadIdx.x;
    if (tb < 2048) {
        int t = tb * 256 + tid;
        int b = t >> 18, i = t & (NQ - 1);
        _Float16 v[40];
#pragma unroll
        for (int c = 0; c < 32; c++)
            v[c] = (_Float16)hid[((size_t)(b * 32 + c)) * NQ + i];
        v[32] = (_Float16)pha[(size_t)b * NQ + i];
#pragma unroll
        for (int c = 33; c < 40; c++) v[c] = (_Float16)0.f;
        _Float16* dst = xt + (size_t)t * 40;
#pragma unroll
        for (int q = 0; q < 5; q++) *(f16x8*)(dst + q * 8) = *(const f16x8*)(v + q * 8);
    } else {
        int t = (tb - 2048) * 256 + tid;
        int xq = t & 511;
        int rest = t >> 9;
        int oy = rest & 2047;
        int b  = rest >> 11;
        const float* src = pha + (size_t)b * NQ;
        float sy = oy * 0.25f - 0.375f;
        sy = fminf(fmaxf(sy, 0.0f), 511.0f);
        int y0 = (int)sy; int y1i = min(y0 + 1, 511);
        float fy = sy - (float)y0;
        float rv[4];
#pragma unroll
        for (int j = 0; j < 4; j++) {
            int ox = xq * 4 + j;
            float sx = ox * 0.25f - 0.375f;
            sx = fminf(fmaxf(sx, 0.0f), 511.0f);
            int x0 = (int)sx; int x1i = min(x0 + 1, 511);
            float fx = sx - (float)x0;
            float v00 = src[y0 * 512 + x0],  v01 = src[y0 * 512 + x1i];
            float v10 = src[y1i * 512 + x0], v11 = src[y1i * 512 + x1i];
            rv[j] = v00 * (1.f - fy) * (1.f - fx) + v01 * (1.f - fy) * fx
                  + v10 * fy * (1.f - fx)         + v11 * fy * fx;
        }
        float4 r4 = make_float4(rv[0], rv[1], rv[2], rv[3]);
        *reinterpret_cast<float4*>(out + (size_t)b * 4194304 + (size_t)oy * 2048 + xq * 4) = r4;
    }
}

// standalone upsample (fallback path only)
__global__ void upsample_kernel(const float* __restrict__ pha, float* __restrict__ out) {
    int t = blockIdx.x * 256 + threadIdx.x;
    int xq = t & 511;
    int rest = t >> 9;
    int oy = rest & 2047;
    int b  = rest >> 11;
    const float* src = pha + (size_t)b * NQ;
    float sy = oy * 0.25f - 0.375f;
    sy = fminf(fmaxf(sy, 0.0f), 511.0f);
    int y0 = (int)sy; int y1i = min(y0 + 1, 511);
    float fy = sy - (float)y0;
    float rv[4];
#pragma unroll
    for (int j = 0; j < 4; j++) {
        int ox = xq * 4 + j;
        float sx = ox * 0.25f - 0.375f;
        sx = fminf(fmaxf(sx, 0.0f), 511.0f);
        int x0 = (int)sx; int x1i = min(x0 + 1, 511);
        float fx = sx - (float)x0;
        float v00 = src[y0 * 512 + x0],  v01 = src[y0 * 512 + x1i];
        float v10 = src[y1i * 512 + x0], v11 = src[y1i * 512 + x1i];
        rv[j] = v00 * (1.f - fy) * (1.f - fx) + v01 * (1.f - fy) * fx
              + v10 * fy * (1.f - fx)         + v11 * fy * fx;
    }
    float4 r4 = make_float4(rv[0], rv[1], rv[2], rv[3]);
    *reinterpret_cast<float4*>(out + (size_t)b * 4194304 + (size_t)oy * 2048 + xq * 4) = r4;
}

// ================= L1: hist round 0 (11-bit bins, pre-zeroed) + prep + tu =================
__global__ void l1_kernel(const float* __restrict__ err, uint32_t* st,
                          const float* __restrict__ w1, const float* __restrict__ g1,
                          const float* __restrict__ b1, const float* __restrict__ m1,
                          const float* __restrict__ v1,
                          const float* __restrict__ w2, const float* __restrict__ g2,
                          const float* __restrict__ b2, const float* __restrict__ m2,
                          const float* __restrict__ v2,
                          const float* __restrict__ w3, const float* __restrict__ g3,
                          const float* __restrict__ b3, const float* __restrict__ m3,
                          const float* __restrict__ v3,
                          const float* __restrict__ w4, const float* __restrict__ b4,
                          char* __restrict__ ws,
                          const float* __restrict__ hid, const float* __restrict__ pha,
                          _Float16* __restrict__ xt, float* __restrict__ out, int tu_base) {
    int blk = blockIdx.x, tid = threadIdx.x;
    if (blk < 2048) {
        __shared__ uint32_t h[2048];
        for (int i = tid; i < 2048; i += 256) h[i] = 0u;
        __syncthreads();
        int t = blk * 256 + tid;
        int b = t >> 18;
        uint32_t bits = __float_as_uint(err[t]);
        atomicAdd(&h[bits >> 21], 1u);
        __syncthreads();
        uint32_t* g = hist_base(st, 0, b);
        for (int i = tid; i < 2048; i += 256) {
            uint32_t v = h[i];
            if (v) atomicAdd(&g[i], v);
        }
    } else if (blk < 2112) {
        prep_work(blk - 2048, w1, g1, b1, m1, v1, w2, g2, b2, m2, v2,
                  w3, g3, b3, m3, v3, w4, b4, ws);
    } else {
        tu_work(blk - 2112 + tu_base, hid, pha, xt, out);
    }
}

// ================= hist rounds 1..2 (chain-scan) =================
__global__ void hist_kernel(const float* __restrict__ err, uint32_t* st, int round,
                            const float* __restrict__ hid, const float* __restrict__ pha,
                            _Float16* __restrict__ xt, float* __restrict__ out, int tu_base) {
    if (blockIdx.x >= 2048) { tu_work(blockIdx.x - 2048 + tu_base, hid, pha, xt, out); return; }
    __shared__ uint32_t h[2048];
    int nb = (round == 1) ? 11 : 10;
    int nbins = 1 << nb;
    for (int i = threadIdx.x; i < nbins; i += 256) h[i] = 0u;
    int t = blockIdx.x * 256 + threadIdx.x;
    int b = t >> 18;
    uint32_t pref, rem;
    chain_scan(st, b, round, &pref, &rem);
    __syncthreads();
    uint32_t bits = __float_as_uint(err[t]);
    bool match;
    uint32_t bin;
    if (round == 1) { match = (bits >> 21) == (pref >> 21); bin = (bits >> 10) & 0x7FFu; }
    else            { match = (bits >> 10) == (pref >> 10); bin = bits & 0x3FFu; }
    if (match) atomicAdd(&h[bin], 1u);
    __syncthreads();
    uint32_t* g = hist_base(st, round, b);
    for (int i = threadIdx.x; i < nbins; i += 256) {
        uint32_t v = h[i];
        if (v) atomicAdd(&g[i], v);
    }
}

// ================= ccount: chain 3 rounds, publish T/need + packed sel|eq counts =================
__global__ void ccount_kernel(const float* __restrict__ err, uint32_t* st,
                              const float* __restrict__ hid, const float* __restrict__ pha,
                              _Float16* __restrict__ xt, float* __restrict__ out, int tu_base) {
    if (blockIdx.x >= 1024) { tu_work(blockIdx.x - 1024 + tu_base, hid, pha, xt, out); return; }
    __shared__ uint32_t wsum[16];
    int blk = blockIdx.x, tid = threadIdx.x;
    int b = blk >> 9, base = (blk & 511) << 9;
    uint32_t T, need;
    chain_scan(st, b, 3, &T, &need);
    if ((blk & 511) == 0 && tid == 0) {
        atomicExch(&st[4 + b], T);
        atomicExch(&st[6 + b], need);
    }
    uint32_t b0 = __float_as_uint(err[b * NQ + base + tid]);
    uint32_t b1 = __float_as_uint(err[b * NQ + base + 256 + tid]);
    unsigned long long m0s = __ballot(b0 > T), m1s = __ballot(b1 > T);
    unsigned long long m0e = __ballot(b0 == T), m1e = __ballot(b1 == T);
    int w = tid >> 6, lane = tid & 63;
    if (lane == 0) {
        wsum[w]      = (uint32_t)__popcll(m0s);
        wsum[4 + w]  = (uint32_t)__popcll(m1s);
        wsum[8 + w]  = (uint32_t)__popcll(m0e);
        wsum[12 + w] = (uint32_t)__popcll(m1e);
    }
    __syncthreads();
    if (tid == 0) {
        uint32_t s = 0, e = 0;
        for (int j = 0; j < 8; j++) { s += wsum[j]; e += wsum[8 + j]; }
        st[WS_BCNT + blk] = s | (e << 16);
    }
}

// ================= cplace: deterministic sel + tie placement =================
__global__ void cplace_kernel(const float* __restrict__ err, uint32_t* st,
                              float* __restrict__ refout,
                              const float* __restrict__ hid, const float* __restrict__ pha,
                              _Float16* __restrict__ xt, float* __restrict__ out, int tu_base) {
    if (blockIdx.x >= 1024) { tu_work(blockIdx.x - 1024 + tu_base, hid, pha, xt, out); return; }
    __shared__ uint32_t wcS[8], wcE[8];
    __shared__ uint32_t redP[4], redE[4];
    int blk = blockIdx.x, tid = threadIdx.x;
    int b = blk >> 9, base = (blk & 511) << 9;
    int w = tid >> 6, lane = tid & 63;
    uint32_t T = st[4 + b];
    uint32_t need = st[6 + b];
    uint32_t myp = blk & 511;
    uint32_t p0 = st[WS_BCNT + b * 512 + 2 * tid];
    uint32_t p1 = st[WS_BCNT + b * 512 + 2 * tid + 1];
    uint32_t s0c = p0 & 0xFFFFu, s1c = p1 & 0xFFFFu;
    uint32_t e0c = p0 >> 16,     e1c = p1 >> 16;
    uint32_t vP = (((uint32_t)(2 * tid) < myp) ? s0c : 0u)
                + (((uint32_t)(2 * tid + 1) < myp) ? s1c : 0u)
                + ((s0c + s1c) << 16);
    uint32_t vE = (((uint32_t)(2 * tid) < myp) ? e0c : 0u)
                + (((uint32_t)(2 * tid + 1) < myp) ? e1c : 0u);
    for (int o = 1; o < 64; o <<= 1) { vP += __shfl_xor(vP, o); vE += __shfl_xor(vE, o); }
    if (lane == 0) { redP[w] = vP; redE[w] = vE; }
    __syncthreads();
    uint32_t sumP = redP[0] + redP[1] + redP[2] + redP[3];
    uint32_t eqbase   = redE[0] + redE[1] + redE[2] + redE[3];
    uint32_t selbase  = sumP & 0xFFFFu;
    uint32_t selTotal = sumP >> 16;

    int i0 = base + tid, i1 = base + 256 + tid;
    uint32_t b0 = __float_as_uint(err[b * NQ + i0]);
    uint32_t b1 = __float_as_uint(err[b * NQ + i1]);
    bool s0 = b0 > T, s1 = b1 > T;
    bool q0 = b0 == T, q1 = b1 == T;
    unsigned long long m0s = __ballot(s0), m1s = __ballot(s1);
    unsigned long long m0e = __ballot(q0), m1e = __ballot(q1);
    if (lane == 0) {
        wcS[w] = (uint32_t)__popcll(m0s); wcS[4 + w] = (uint32_t)__popcll(m1s);
        wcE[w] = (uint32_t)__popcll(m0e); wcE[4 + w] = (uint32_t)__popcll(m1e);
    }
    __syncthreads();
    uint32_t tot0S = wcS[0] + wcS[1] + wcS[2] + wcS[3];
    uint32_t tot0E = wcE[0] + wcE[1] + wcE[2] + wcE[3];
    uint32_t preS0 = 0, preS1 = tot0S, preE0 = 0, preE1 = tot0E;
    for (int j = 0; j < w; j++) {
        preS0 += wcS[j]; preS1 += wcS[4 + j];
        preE0 += wcE[j]; preE1 += wcE[4 + j];
    }
    unsigned long long lt = (1ull << lane) - 1ull;
    float rv0 = s0 ? 1.0f : 0.0f;
    float rv1 = s1 ? 1.0f : 0.0f;
    if (s0) {
        uint32_t slot = selbase + preS0 + (uint32_t)__popcll(m0s & lt);
        if (slot < K_SEL) st[WS_SEL + b * K_SEL + slot] = (uint32_t)i0;
    }
    if (s1) {
        uint32_t slot = selbase + preS1 + (uint32_t)__popcll(m1s & lt);
        if (slot < K_SEL) st[WS_SEL + b * K_SEL + slot] = (uint32_t)i1;
    }
    if (q0) {
        uint32_t rank = eqbase + preE0 + (uint32_t)__popcll(m0e & lt);
        if (rank < need) {
            uint32_t slot = selTotal + rank;
            if (slot < K_SEL) st[WS_SEL + b * K_SEL + slot] = (uint32_t)i0;
            rv0 = (T != 0u) ? 1.0f : 0.0f;
        }
    }
    if (q1) {
        uint32_t rank = eqbase + preE1 + (uint32_t)__popcll(m1e & lt);
        if (rank < need) {
            uint32_t slot = selTotal + rank;
            if (slot < K_SEL) st[WS_SEL + b * K_SEL + slot] = (uint32_t)i1;
            rv1 = (T != 0u) ? 1.0f : 0.0f;
        }
    }
    refout[b * NQ + i0] = rv0;
    refout[b * NQ + i1] = rv1;
}

// ================= MFMA patch CNN: 2 waves / patch (R16-proven, 128 threads) =================
__device__ __forceinline__ f16x8 ldfrag(const _Float16* wf, int frag, int l) {
    return *(const f16x8*)(wf + frag * 512 + l * 8);
}

template<bool XT>
__global__ __launch_bounds__(128) void patch_kernel(
    const float* __restrict__ hid, const float* __restrict__ pha,
    const _Float16* __restrict__ xt,
    const char* __restrict__ ws, float* __restrict__ out) {
    __shared__ _Float16 xs[64][40];
    __shared__ _Float16 y1n[36][40];
    __shared__ _Float16 pool[64][40];
    __shared__ float pha8[64];
    __shared__ float biasL[56];
    float* y3s = (float*)&y1n[0][0];

    const _Float16* wf = (const _Float16*)ws;
    const float* biasG = (const float*)(ws + BIAS_OFF);
    const float* w4r   = (const float*)(ws + W4_OFF);
    const uint32_t* st = (const uint32_t*)(ws + ST_OFF);

    int tid = threadIdx.x, l = tid & 63, wid = tid >> 6;
    int lo = l & 15, hi = l >> 4;
    int bp = blockIdx.x;
    int b = (bp >= K_SEL) ? 1 : 0;
    int pi = bp - b * K_SEL;
    uint32_t idx = st[WS_SEL + b * K_SEL + pi] & 0x3FFFFu;
    int hq = (int)(idx >> 9), wq = (int)(idx & 511u);

    if (tid < 53) biasL[tid] = biasG[tid];

    int ry = l >> 3, rx = l & 7;
    int hy = hq * 2 + ry - 3, hx = wq * 2 + rx - 3;
    bool inb = ((unsigned)hy < 1024u) && ((unsigned)hx < 1024u);
    float sy = fminf(fmaxf(hy * 0.5f - 0.25f, 0.f), 511.f);
    float sx = fminf(fmaxf(hx * 0.5f - 0.25f, 0.f), 511.f);
    int y0 = (int)sy, x0 = (int)sx;
    int y1c = min(y0 + 1, 511), x1c = min(x0 + 1, 511);
    float fy = sy - (float)y0, fx = sx - (float)x0;
    int o00 = y0 * 512 + x0, o01 = y0 * 512 + x1c, o10 = y1c * 512 + x0, o11 = y1c * 512 + x1c;
    float w00 = (1.f - fy) * (1.f - fx), w01 = (1.f - fy) * fx;
    float w10 = fy * (1.f - fx), w11 = fy * fx;

    _Float16 hv[16];
    if (XT) {
        if (inb) {
            const _Float16* xtb = xt + (size_t)b * NQ * 40 + (size_t)wid * 16;
            const _Float16* p00 = xtb + (size_t)o00 * 40;
            const _Float16* p01 = xtb + (size_t)o01 * 40;
            const _Float16* p10 = xtb + (size_t)o10 * 40;
            const _Float16* p11 = xtb + (size_t)o11 * 40;
            f16x8 a0 = *(const f16x8*)p00, a1 = *(const f16x8*)(p00 + 8);
            f16x8 b0 = *(const f16x8*)p01, b1 = *(const f16x8*)(p01 + 8);
            f16x8 c0 = *(const f16x8*)p10, c1 = *(const f16x8*)(p10 + 8);
            f16x8 d0 = *(const f16x8*)p11, d1 = *(const f16x8*)(p11 + 8);
#pragma unroll
            for (int j = 0; j < 8; j++) {
                hv[j]     = (_Float16)(w00 * (float)a0[j] + w01 * (float)b0[j]
                                     + w10 * (float)c0[j] + w11 * (float)d0[j]);
                hv[j + 8] = (_Float16)(w00 * (float)a1[j] + w01 * (float)b1[j]
                                     + w10 * (float)c1[j] + w11 * (float)d1[j]);
            }
        } else {
#pragma unroll
            for (int c = 0; c < 16; c++) hv[c] = (_Float16)0.f;
        }
    } else {
        const float* hb = hid + ((size_t)b * 32 + wid * 16) * NQ;
#pragma unroll
        for (int c = 0; c < 16; c++) {
            const float* p = hb + (size_t)c * NQ;
            float v = 0.f;
            if (inb) v = p[o00] * w00 + p[o01] * w01 + p[o10] * w10 + p[o11] * w11;
            hv[c] = (_Float16)v;
        }
    }
    f16x8 h0 = {hv[0], hv[1], hv[2], hv[3], hv[4], hv[5], hv[6], hv[7]};
    f16x8 h1 = {hv[8], hv[9], hv[10], hv[11], hv[12], hv[13], hv[14], hv[15]};
    {
        _Float16* xrow = &xs[l][wid * 16];
        *(f16x8*)xrow = h0;
        *((f16x8*)xrow + 1) = h1;
    }
    f16x8 z8 = {(_Float16)0.f, (_Float16)0.f, (_Float16)0.f, (_Float16)0.f,
                (_Float16)0.f, (_Float16)0.f, (_Float16)0.f, (_Float16)0.f};
    if (wid == 1) {
        const float* p = pha + (size_t)b * NQ;
        float v = 0.f;
        if (inb) v = p[o00] * w00 + p[o01] * w01 + p[o10] * w10 + p[o11] * w11;
        pha8[l] = v;
    }
    __syncthreads();

    if (wid == 0) {
        if (l < 48) {
            int py = (l * 43) >> 8, px = l - py * 6;
            _Float16 tap[9];
#pragma unroll
            for (int t = 0; t < 9; t++) {
                int ky = t / 3, kx = t % 3;
                int ip = (py + ky) * 8 + px + kx;
                tap[t] = (_Float16)pha8[ip & 63];
            }
            _Float16* row = &pool[l][0];
            f16x8 r0 = {tap[0], tap[1], tap[2], tap[3], tap[4], tap[5], tap[6], tap[7]};
            f16x8 r1 = z8; r1[0] = tap[8];
            *(f16x8*)row = r0;
            *(f16x8*)(row + 8)  = r1;
            *(f16x8*)(row + 16) = z8;
            *(f16x8*)(row + 24) = z8;
        }
    } else {
        for (int i = l; i < 72; i += 64) {
            *(f16x8*)&y1n[i >> 1][24 + (i & 1) * 8] = z8;
        }
    }
    __syncthreads();

    f32x4 zf = {0.f, 0.f, 0.f, 0.f};
    f32x4 aA0 = zf, aA1 = zf, aB = zf;
    int nA = wid * 16 + lo, nB = 32 + lo;
    int pyA = (nA * 43) >> 8, pxA = nA - pyA * 6;
    int pyB = (nB * 43) >> 8, pxB = nB - pyB * 6;
    {
        f16x8 A0 = ldfrag(wf, 36, l), A1 = ldfrag(wf, 37, l);
        f16x8 BA = *(const f16x8*)&pool[nA][hi * 8];
        f16x8 BB = *(const f16x8*)&pool[nB][hi * 8];
        aA0 = MFMA16(A0, BA, aA0);
        aA1 = MFMA16(A1, BA, aA1);
        aB  = MFMA16(wid ? A1 : A0, BB, aB);
    }
#pragma unroll
    for (int ky = 0; ky < 3; ky++) {
#pragma unroll
        for (int kt = 0; kt < 3; kt++) {
            f16x8 A0 = ldfrag(wf, ky * 6 + kt * 2 + 0, l);
            f16x8 A1 = ldfrag(wf, ky * 6 + kt * 2 + 1, l);
            int rA = ((pyA + ky) * 8 + pxA + kt) & 63;
            int rB = ((pyB + ky) * 8 + pxB + kt) & 63;
            f16x8 BA = *(const f16x8*)&xs[rA][hi * 8];
            f16x8 BB = *(const f16x8*)&xs[rB][hi * 8];
            aA0 = MFMA16(A0, BA, aA0);
            aA1 = MFMA16(A1, BA, aA1);
            aB  = MFMA16(wid ? A1 : A0, BB, aB);
        }
    }
    {
        f32x4 accs[3] = {aA0, aA1, aB};
        int mts[3] = {0, 1, wid};
        int nts[3] = {wid, wid, 2};
#pragma unroll
        for (int f = 0; f < 3; f++) {
            int n = nts[f] * 16 + lo;
            int ocb = mts[f] * 16 + hi * 4;
            if (n < 36 && ocb < 24) {
                f16x4 hh;
                hh[0] = (_Float16)fmaxf(accs[f][0] + biasL[ocb + 0], 0.f);
                hh[1] = (_Float16)fmaxf(accs[f][1] + biasL[ocb + 1], 0.f);
                hh[2] = (_Float16)fmaxf(accs[f][2] + biasL[ocb + 2], 0.f);
                hh[3] = (_Float16)fmaxf(accs[f][3] + biasL[ocb + 3], 0.f);
                *(f16x4*)&y1n[n][ocb] = hh;
            }
        }
    }
    __syncthreads();

    if (wid == 0) {
        f32x4 a2 = zf;
        int qy = lo >> 2, qx = lo & 3;
#pragma unroll
        for (int ky = 0; ky < 3; ky++) {
#pragma unroll
            for (int kt = 0; kt < 3; kt++) {
                f16x8 A = ldfrag(wf, 18 + ky * 3 + kt, l);
                int k = kt * 32 + hi * 8;
                const _Float16* bptr;
                if (k < 72) {
                    int kx = k / 24, ci0 = k - kx * 24;
                    bptr = &y1n[(qy + ky) * 6 + qx + kx][ci0];
                } else {
                    bptr = &y1n[0][24];
                }
                f16x8 B = *(const f16x8*)bptr;
                a2 = MFMA16(A, B, a2);
            }
        }
        int ocb = hi * 4;
        f16x4 hh;
        hh[0] = (_Float16)fmaxf(a2[0] + biasL[24 + ocb + 0], 0.f);
        hh[1] = (_Float16)fmaxf(a2[1] + biasL[24 + ocb + 1], 0.f);
        hh[2] = (_Float16)fmaxf(a2[2] + biasL[24 + ocb + 2], 0.f);
        hh[3] = (_Float16)fmaxf(a2[3] + biasL[24 + ocb + 3], 0.f);
#pragma unroll
        for (int dy = 0; dy < 2; dy++)
#pragma unroll
            for (int dx = 0; dx < 2; dx++) {
                int row = (2 * (lo >> 2) + dy) * 8 + 2 * (lo & 3) + dx;
                *(f16x4*)&pool[row][ocb] = hh;
            }
    } else {
        *(f16x8*)&pool[l][16] = z8;
        *(f16x8*)&pool[l][24] = z8;
    }
    __syncthreads();

    f32x4 aC = zf, aD = zf;
    int nC = wid * 16 + lo, nD = 32 + lo;
    int pyC = (nC * 43) >> 8, pxC = nC - pyC * 6;
    int pyD = (nD * 43) >> 8, pxD = nD - pyD * 6;
#pragma unroll
    for (int s = 0; s < 9; s++) {
        int ky = s / 3, kx = s % 3;
        f16x8 A = ldfrag(wf, 27 + s, l);
        f16x8 BC = *(const f16x8*)&pool[((pyC + ky) * 8 + pxC + kx) & 63][hi * 8];
        aC = MFMA16(A, BC, aC);
        if (wid) {
            f16x8 BD = *(const f16x8*)&pool[((pyD + ky) * 8 + pxD + kx) & 63][hi * 8];
            aD = MFMA16(A, BD, aD);
        }
    }
    __syncthreads();
    {
        int ocb = hi * 4;
        f32x4 accs[2] = {aC, aD};
        int nts[2] = {wid, 2};
        int cnt = wid ? 2 : 1;
        for (int f = 0; f < cnt; f++) {
            int n = nts[f] * 16 + lo;
            if (n < 36) {
                f32x4 v;
#pragma unroll
                for (int r = 0; r < 4; r++) {
                    float bb = (ocb + r < 12) ? biasL[40 + ocb + r] : 0.f;
                    float x = accs[f][r] + bb;
                    v[r] = (ocb + r < 12) ? fmaxf(x, 0.f) : 0.f;
                }
                *(f32x4*)&y3s[n * 16 + ocb] = v;
            }
        }
    }
    __syncthreads();

    if (wid == 0) {
        int r4 = lo >> 2, c4 = lo & 3, cig = hi;
        float acc = 0.f;
#pragma unroll
        for (int t = 0; t < 9; t++) {
            int ky = t / 3, kx = t % 3;
            const f32x4 xv = *(const f32x4*)&y3s[((r4 + ky) * 6 + c4 + kx) * 16 + cig * 4];
            const f32x4 wv = *(const f32x4*)(w4r + t * 16 + cig * 4);
            acc += xv[0] * wv[0] + xv[1] * wv[1] + xv[2] * wv[2] + xv[3] * wv[3];
        }
        acc += __shfl_xor(acc, 32);
        acc += __shfl_xor(acc, 16);
        if (l < 16) {
            out[(size_t)b * 4194304 + (size_t)(hq * 4 + r4) * 2048 + (wq * 4 + c4)] = acc + biasL[52];
        }
    }
}

extern "C" void kernel_launch(void* const* d_in, const int* in_sizes, int n_in,
                              void* d_out, int out_size, void* d_ws, size_t ws_size,
                              hipStream_t stream) {
    const float* pha = (const float*)d_in[0];
    const float* err = (const float*)d_in[1];
    const float* hid = (const float*)d_in[2];
    const float* w1  = (const float*)d_in[3];
    const float* g1  = (const float*)d_in[4];
    const float* bb1 = (const float*)d_in[5];
    const float* m1  = (const float*)d_in[6];
    const float* v1  = (const float*)d_in[7];
    const float* w2  = (const float*)d_in[8];
    const float* g2  = (const float*)d_in[9];
    const float* bb2 = (const float*)d_in[10];
    const float* m2  = (const float*)d_in[11];
    const float* v2  = (const float*)d_in[12];
    const float* w3  = (const float*)d_in[13];
    const float* g3  = (const float*)d_in[14];
    const float* bb3 = (const float*)d_in[15];
    const float* m3  = (const float*)d_in[16];
    const float* v3  = (const float*)d_in[17];
    const float* w4  = (const float*)d_in[18];
    const float* b4  = (const float*)d_in[19];

    float* out    = (float*)d_out;
    float* refout = out + (size_t)NB * 4194304;
    char* ws      = (char*)d_ws;
    uint32_t* st  = (uint32_t*)(ws + ST_OFF);
    _Float16* xt  = (_Float16*)(ws + XT_OFF);
    bool use_xt   = (ws_size >= WS_NEED);     // constant across calls -> deterministic

    // zero hist bins + header (stream-ordered; graph-capture safe)
    hipMemsetAsync(st, 0, (16 + 12288) * sizeof(uint32_t), stream);

    if (use_xt) {
        const int NTU = 10240, SLICE = 2048;  // tu blocks over 5 launches
        int off = 0;
        l1_kernel<<<2112 + SLICE, 256, 0, stream>>>(err, st, w1, g1, bb1, m1, v1,
                                                    w2, g2, bb2, m2, v2, w3, g3, bb3, m3, v3,
                                                    w4, b4, ws, hid, pha, xt, out, off);
        off += SLICE;
        for (int r = 1; r < 3; r++) {
            hist_kernel<<<2048 + SLICE, 256, 0, stream>>>(err, st, r, hid, pha, xt, out, off);
            off += SLICE;
        }
        ccount_kernel<<<1024 + SLICE, 256, 0, stream>>>(err, st, hid, pha, xt, out, off);
        off += SLICE;
        cplace_kernel<<<1024 + (NTU - off), 256, 0, stream>>>(err, st, refout, hid, pha, xt, out, off);
        patch_kernel<true><<<2 * K_SEL, 128, 0, stream>>>(hid, pha, xt, ws, out);
    } else {
        upsample_kernel<<<8192, 256, 0, stream>>>(pha, out);
        l1_kernel<<<2112, 256, 0, stream>>>(err, st, w1, g1, bb1, m1, v1,
                                            w2, g2, bb2, m2, v2, w3, g3, bb3, m3, v3,
                                            w4, b4, ws, hid, pha, xt, out, 0);
        for (int r = 1; r < 3; r++)
            hist_kernel<<<2048, 256, 0, stream>>>(err, st, r, hid, pha, xt, out, 0);
        ccount_kernel<<<1024, 256, 0, stream>>>(err, st, hid, pha, xt, out, 0);
        cplace_kernel<<<1024, 256, 0, stream>>>(err, st, refout, hid, pha, xt, out, 0);
        patch_kernel<false><<<2 * K_SEL, 128, 0, stream>>>(hid, pha, xt, ws, out);
    }
}

// Round 19
// 135.064 us; speedup vs baseline: 1.5936x; 1.5936x over previous
//
#include <hip/hip_runtime.h>
#include <stdint.h>

#define K_SEL 5000
#define NQ    262144   // 512*512
#define NB    2

// ---------------- ws layout (bytes) ----------------
#define BIAS_OFF 38912
#define W4_OFF   39424
#define ST_OFF   40960
#define XT_OFF   135168                      // channels-last f16 buffer (clear of st)
#define XT_BYTES ((size_t)NB * NQ * 40 * 2)  // 41,943,040
#define WS_NEED  (XT_OFF + XT_BYTES)

// ---------------- topk state (uint32 word offsets within st) ----------------
// [4..5] T  [6..7] need
// [16..2063] hist 4x2x256 ; [2064..12063] selList 2x5000
// [20480..21503] per-block packed counts: sel | (eq<<16)
#define WS_HIST  16
#define WS_SEL   2064
#define WS_BCNT  20480

typedef _Float16 f16x8 __attribute__((ext_vector_type(8)));
typedef _Float16 f16x4 __attribute__((ext_vector_type(4)));
typedef float    f32x4 __attribute__((ext_vector_type(4)));
#define MFMA16(a,b,c) __builtin_amdgcn_mfma_f32_16x16x32_f16(a,b,c,0,0,0)

// ================= prep work (device fn): fold BN, pack MFMA fragments =================
__device__ void prep_work(int bid,
                          const float* __restrict__ w1, const float* __restrict__ g1,
                          const float* __restrict__ b1, const float* __restrict__ m1,
                          const float* __restrict__ v1,
                          const float* __restrict__ w2, const float* __restrict__ g2,
                          const float* __restrict__ b2, const float* __restrict__ m2,
                          const float* __restrict__ v2,
                          const float* __restrict__ w3, const float* __restrict__ g3,
                          const float* __restrict__ b3, const float* __restrict__ m3,
                          const float* __restrict__ v3,
                          const float* __restrict__ w4, const float* __restrict__ b4,
                          char* __restrict__ ws) {
    _Float16* wf = (_Float16*)ws;
    float* bias = (float*)(ws + BIAS_OFF);
    float* w4r  = (float*)(ws + W4_OFF);
    int tid = threadIdx.x;
    for (int t = bid * 256 + tid; t < 38 * 512; t += 64 * 256) {
        int frag = t >> 9, li = (t >> 3) & 63, j = t & 7;
        int lo = li & 15, hi = li >> 4;
        float val = 0.f;
        if (frag < 18) {                                  // conv1
            int ky = frag / 6, r = frag % 6, kx = r >> 1, mt = r & 1;
            int oc = mt * 16 + lo, ci = hi * 8 + j;
            if (oc < 24) val = w1[((oc * 33 + ci) * 3 + ky) * 3 + kx] * g1[oc] * rsqrtf(v1[oc] + 1e-5f);
        } else if (frag < 27) {                           // conv2: k = kx*24 + ci  (k<72)
            int f = frag - 18, ky = f / 3, kt = f % 3;
            int oc = lo, k = kt * 32 + hi * 8 + j;
            if (k < 72) {
                int kx = k / 24, ci = k % 24;
                val = w2[((oc * 24 + ci) * 3 + ky) * 3 + kx] * g2[oc] * rsqrtf(v2[oc] + 1e-5f);
            }
        } else if (frag < 36) {                           // conv3
            int s = frag - 27, ky = s / 3, kx = s % 3;
            int oc = lo, ci = hi * 8 + j;
            if (oc < 12 && ci < 16) val = w3[((oc * 16 + ci) * 3 + ky) * 3 + kx] * g3[oc] * rsqrtf(v3[oc] + 1e-5f);
        } else {                                          // conv1 pha channel
            int mt = frag - 36, oc = mt * 16 + lo, tap = hi * 8 + j;
            if (oc < 24 && tap < 9)
                val = w1[((oc * 33 + 32) * 3 + tap / 3) * 3 + tap % 3] * g1[oc] * rsqrtf(v1[oc] + 1e-5f);
        }
        wf[t] = (_Float16)val;
    }
    if (bid == 0) {
        if (tid < 53) {
            float v;
            if (tid < 24)      { float sc = g1[tid] * rsqrtf(v1[tid] + 1e-5f); v = b1[tid] - m1[tid] * sc; }
            else if (tid < 40) { int c = tid - 24; float sc = g2[c] * rsqrtf(v2[c] + 1e-5f); v = b2[c] - m2[c] * sc; }
            else if (tid < 52) { int c = tid - 40; float sc = g3[c] * rsqrtf(v3[c] + 1e-5f); v = b3[c] - m3[c] * sc; }
            else v = b4[0];
            bias[tid] = v;
        }
        if (tid < 144) { int t9 = tid / 16, ci = tid % 16; w4r[tid] = (ci < 12) ? w4[ci * 9 + t9] : 0.f; }
    }
}

// ================= wave-level chained radix scan over published hist bins =================
__device__ __forceinline__ void chain_scan(const uint32_t* __restrict__ st, int b, int nrounds,
                                           uint32_t* pref_out, uint32_t* rem_out) {
    int lane = threadIdx.x & 63;
    uint32_t pref = 0u, rem = K_SEL;
    for (int r = 0; r < nrounds; r++) {
        const uint32_t* hist = st + WS_HIST + r * 512 + b * 256;
        int binbase = 255 - 4 * lane;
        uint32_t hv0 = hist[binbase], hv1 = hist[binbase - 1],
                 hv2 = hist[binbase - 2], hv3 = hist[binbase - 3];
        uint32_t p = hv0 + hv1 + hv2 + hv3;
        uint32_t cum = p;
        for (int o = 1; o < 64; o <<= 1) {
            uint32_t n = __shfl_up(cum, o);
            if (lane >= o) cum += n;
        }
        unsigned long long bal = __ballot(cum >= rem);
        int first = __ffsll(bal) - 1;
        uint32_t acc = cum - p;
        uint32_t hv[4] = {hv0, hv1, hv2, hv3};
        int ch = binbase;
        for (int q = 0; q < 4; q++) {
            if (acc + hv[q] >= rem) { ch = binbase - q; break; }
            acc += hv[q];
        }
        uint32_t chosen = (uint32_t)__shfl((int)ch, first);
        uint32_t nrem   = (uint32_t)__shfl((int)(rem - acc), first);
        pref |= chosen << (24 - 8 * r);
        rem = nrem;
    }
    *pref_out = pref;
    *rem_out = rem;
}

// ================= tu work: channels-last transpose (tb<2048) / 4x upsample =================
__device__ __forceinline__ void tu_work(int tb, const float* __restrict__ hid,
                                        const float* __restrict__ pha,
                                        _Float16* __restrict__ xt,
                                        float* __restrict__ out) {
    int tid = threadIdx.x;
    if (tb < 2048) {
        int t = tb * 256 + tid;                    // 524288 total
        int b = t >> 18, i = t & (NQ - 1);
        _Float16 v[40];
#pragma unroll
        for (int c = 0; c < 32; c++)
            v[c] = (_Float16)hid[((size_t)(b * 32 + c)) * NQ + i];
        v[32] = (_Float16)pha[(size_t)b * NQ + i];
#pragma unroll
        for (int c = 33; c < 40; c++) v[c] = (_Float16)0.f;
        _Float16* dst = xt + (size_t)t * 40;
#pragma unroll
        for (int q = 0; q < 5; q++) *(f16x8*)(dst + q * 8) = *(const f16x8*)(v + q * 8);
    } else {
        int t = (tb - 2048) * 256 + tid;           // 2097152 total
        int xq = t & 511;
        int rest = t >> 9;
        int oy = rest & 2047;
        int b  = rest >> 11;
        const float* src = pha + (size_t)b * NQ;
        float sy = oy * 0.25f - 0.375f;
        sy = fminf(fmaxf(sy, 0.0f), 511.0f);
        int y0 = (int)sy; int y1i = min(y0 + 1, 511);
        float fy = sy - (float)y0;
        float rv[4];
#pragma unroll
        for (int j = 0; j < 4; j++) {
            int ox = xq * 4 + j;
            float sx = ox * 0.25f - 0.375f;
            sx = fminf(fmaxf(sx, 0.0f), 511.0f);
            int x0 = (int)sx; int x1i = min(x0 + 1, 511);
            float fx = sx - (float)x0;
            float v00 = src[y0 * 512 + x0],  v01 = src[y0 * 512 + x1i];
            float v10 = src[y1i * 512 + x0], v11 = src[y1i * 512 + x1i];
            rv[j] = v00 * (1.f - fy) * (1.f - fx) + v01 * (1.f - fy) * fx
                  + v10 * fy * (1.f - fx)         + v11 * fy * fx;
        }
        float4 r4 = make_float4(rv[0], rv[1], rv[2], rv[3]);
        *reinterpret_cast<float4*>(out + (size_t)b * 4194304 + (size_t)oy * 2048 + xq * 4) = r4;
    }
}

// standalone upsample (fallback path only)
__global__ void upsample_kernel(const float* __restrict__ pha, float* __restrict__ out) {
    int t = blockIdx.x * 256 + threadIdx.x;
    int xq = t & 511;
    int rest = t >> 9;
    int oy = rest & 2047;
    int b  = rest >> 11;
    const float* src = pha + (size_t)b * NQ;
    float sy = oy * 0.25f - 0.375f;
    sy = fminf(fmaxf(sy, 0.0f), 511.0f);
    int y0 = (int)sy; int y1i = min(y0 + 1, 511);
    float fy = sy - (float)y0;
    float rv[4];
#pragma unroll
    for (int j = 0; j < 4; j++) {
        int ox = xq * 4 + j;
        float sx = ox * 0.25f - 0.375f;
        sx = fminf(fmaxf(sx, 0.0f), 511.0f);
        int x0 = (int)sx; int x1i = min(x0 + 1, 511);
        float fx = sx - (float)x0;
        float v00 = src[y0 * 512 + x0],  v01 = src[y0 * 512 + x1i];
        float v10 = src[y1i * 512 + x0], v11 = src[y1i * 512 + x1i];
        rv[j] = v00 * (1.f - fy) * (1.f - fx) + v01 * (1.f - fy) * fx
              + v10 * fy * (1.f - fx)         + v11 * fy * fx;
    }
    float4 r4 = make_float4(rv[0], rv[1], rv[2], rv[3]);
    *reinterpret_cast<float4*>(out + (size_t)b * 4194304 + (size_t)oy * 2048 + xq * 4) = r4;
}

// ================= L1: hist round 0 (bins pre-zeroed by memset) + prep + tu =================
__global__ void l1_kernel(const float* __restrict__ err, uint32_t* st,
                          const float* __restrict__ w1, const float* __restrict__ g1,
                          const float* __restrict__ b1, const float* __restrict__ m1,
                          const float* __restrict__ v1,
                          const float* __restrict__ w2, const float* __restrict__ g2,
                          const float* __restrict__ b2, const float* __restrict__ m2,
                          const float* __restrict__ v2,
                          const float* __restrict__ w3, const float* __restrict__ g3,
                          const float* __restrict__ b3, const float* __restrict__ m3,
                          const float* __restrict__ v3,
                          const float* __restrict__ w4, const float* __restrict__ b4,
                          char* __restrict__ ws,
                          const float* __restrict__ hid, const float* __restrict__ pha,
                          _Float16* __restrict__ xt, float* __restrict__ out, int tu_base) {
    int blk = blockIdx.x, tid = threadIdx.x;
    if (blk < 2048) {
        __shared__ uint32_t h[256];
        h[tid] = 0u;
        __syncthreads();
        int t = blk * 256 + tid;
        int b = t >> 18;
        uint32_t bits = __float_as_uint(err[t]);
        atomicAdd(&h[bits >> 24], 1u);
        __syncthreads();
        uint32_t v = h[tid];
        if (v) atomicAdd(&st[WS_HIST + b * 256 + tid], v);
    } else if (blk < 2112) {
        prep_work(blk - 2048, w1, g1, b1, m1, v1, w2, g2, b2, m2, v2,
                  w3, g3, b3, m3, v3, w4, b4, ws);
    } else {
        tu_work(blk - 2112 + tu_base, hid, pha, xt, out);
    }
}

// ================= hist rounds 1..3 (chain-scan) =================
__global__ void hist_kernel(const float* __restrict__ err, uint32_t* st, int round,
                            const float* __restrict__ hid, const float* __restrict__ pha,
                            _Float16* __restrict__ xt, float* __restrict__ out, int tu_base) {
    if (blockIdx.x >= 2048) { tu_work(blockIdx.x - 2048 + tu_base, hid, pha, xt, out); return; }
    __shared__ uint32_t h[256];
    h[threadIdx.x] = 0u;
    int t = blockIdx.x * 256 + threadIdx.x;
    int b = t >> 18;
    uint32_t pref, rem;
    chain_scan(st, b, round, &pref, &rem);
    __syncthreads();
    uint32_t bits = __float_as_uint(err[t]);
    int shift = 24 - 8 * round;
    bool match = ((bits >> (shift + 8)) == (pref >> (shift + 8)));
    if (match) atomicAdd(&h[(bits >> shift) & 255u], 1u);
    __syncthreads();
    uint32_t v = h[threadIdx.x];
    if (v) atomicAdd(&st[WS_HIST + round * 512 + b * 256 + threadIdx.x], v);
}

// ================= ccount: chain 4 rounds, publish T/need + packed sel|eq counts =================
__global__ void ccount_kernel(const float* __restrict__ err, uint32_t* st,
                              const float* __restrict__ hid, const float* __restrict__ pha,
                              _Float16* __restrict__ xt, float* __restrict__ out, int tu_base) {
    if (blockIdx.x >= 1024) { tu_work(blockIdx.x - 1024 + tu_base, hid, pha, xt, out); return; }
    __shared__ uint32_t wsum[16];
    int blk = blockIdx.x, tid = threadIdx.x;
    int b = blk >> 9, base = (blk & 511) << 9;
    uint32_t T, need;
    chain_scan(st, b, 4, &T, &need);
    if ((blk & 511) == 0 && tid == 0) {
        atomicExch(&st[4 + b], T);
        atomicExch(&st[6 + b], need);
    }
    uint32_t b0 = __float_as_uint(err[b * NQ + base + tid]);
    uint32_t b1 = __float_as_uint(err[b * NQ + base + 256 + tid]);
    unsigned long long m0s = __ballot(b0 > T), m1s = __ballot(b1 > T);
    unsigned long long m0e = __ballot(b0 == T), m1e = __ballot(b1 == T);
    int w = tid >> 6, lane = tid & 63;
    if (lane == 0) {
        wsum[w]      = (uint32_t)__popcll(m0s);
        wsum[4 + w]  = (uint32_t)__popcll(m1s);
        wsum[8 + w]  = (uint32_t)__popcll(m0e);
        wsum[12 + w] = (uint32_t)__popcll(m1e);
    }
    __syncthreads();
    if (tid == 0) {
        uint32_t s = 0, e = 0;
        for (int j = 0; j < 8; j++) { s += wsum[j]; e += wsum[8 + j]; }
        st[WS_BCNT + blk] = s | (e << 16);
    }
}

// ================= cplace: deterministic sel + tie placement (select fused) =================
__global__ void cplace_kernel(const float* __restrict__ err, uint32_t* st,
                              float* __restrict__ refout,
                              const float* __restrict__ hid, const float* __restrict__ pha,
                              _Float16* __restrict__ xt, float* __restrict__ out, int tu_base) {
    if (blockIdx.x >= 1024) { tu_work(blockIdx.x - 1024 + tu_base, hid, pha, xt, out); return; }
    __shared__ uint32_t wcS[8], wcE[8];
    __shared__ uint32_t redP[4], redE[4];
    int blk = blockIdx.x, tid = threadIdx.x;
    int b = blk >> 9, base = (blk & 511) << 9;
    int w = tid >> 6, lane = tid & 63;
    uint32_t T = st[4 + b];                        // published by ccount launch
    uint32_t need = st[6 + b];
    uint32_t myp = blk & 511;
    uint32_t p0 = st[WS_BCNT + b * 512 + 2 * tid];
    uint32_t p1 = st[WS_BCNT + b * 512 + 2 * tid + 1];
    uint32_t s0c = p0 & 0xFFFFu, s1c = p1 & 0xFFFFu;
    uint32_t e0c = p0 >> 16,     e1c = p1 >> 16;
    uint32_t vP = (((uint32_t)(2 * tid) < myp) ? s0c : 0u)
                + (((uint32_t)(2 * tid + 1) < myp) ? s1c : 0u)
                + ((s0c + s1c) << 16);
    uint32_t vE = (((uint32_t)(2 * tid) < myp) ? e0c : 0u)
                + (((uint32_t)(2 * tid + 1) < myp) ? e1c : 0u);
    for (int o = 1; o < 64; o <<= 1) { vP += __shfl_xor(vP, o); vE += __shfl_xor(vE, o); }
    if (lane == 0) { redP[w] = vP; redE[w] = vE; }
    __syncthreads();
    uint32_t sumP = redP[0] + redP[1] + redP[2] + redP[3];
    uint32_t eqbase   = redE[0] + redE[1] + redE[2] + redE[3];
    uint32_t selbase  = sumP & 0xFFFFu;
    uint32_t selTotal = sumP >> 16;

    int i0 = base + tid, i1 = base + 256 + tid;
    uint32_t b0 = __float_as_uint(err[b * NQ + i0]);
    uint32_t b1 = __float_as_uint(err[b * NQ + i1]);
    bool s0 = b0 > T, s1 = b1 > T;
    bool q0 = b0 == T, q1 = b1 == T;
    unsigned long long m0s = __ballot(s0), m1s = __ballot(s1);
    unsigned long long m0e = __ballot(q0), m1e = __ballot(q1);
    if (lane == 0) {
        wcS[w] = (uint32_t)__popcll(m0s); wcS[4 + w] = (uint32_t)__popcll(m1s);
        wcE[w] = (uint32_t)__popcll(m0e); wcE[4 + w] = (uint32_t)__popcll(m1e);
    }
    __syncthreads();
    uint32_t tot0S = wcS[0] + wcS[1] + wcS[2] + wcS[3];
    uint32_t tot0E = wcE[0] + wcE[1] + wcE[2] + wcE[3];
    uint32_t preS0 = 0, preS1 = tot0S, preE0 = 0, preE1 = tot0E;
    for (int j = 0; j < w; j++) {
        preS0 += wcS[j]; preS1 += wcS[4 + j];
        preE0 += wcE[j]; preE1 += wcE[4 + j];
    }
    unsigned long long lt = (1ull << lane) - 1ull;
    float rv0 = s0 ? 1.0f : 0.0f;
    float rv1 = s1 ? 1.0f : 0.0f;
    if (s0) {
        uint32_t slot = selbase + preS0 + (uint32_t)__popcll(m0s & lt);
        if (slot < K_SEL) st[WS_SEL + b * K_SEL + slot] = (uint32_t)i0;
    }
    if (s1) {
        uint32_t slot = selbase + preS1 + (uint32_t)__popcll(m1s & lt);
        if (slot < K_SEL) st[WS_SEL + b * K_SEL + slot] = (uint32_t)i1;
    }
    if (q0) {
        uint32_t rank = eqbase + preE0 + (uint32_t)__popcll(m0e & lt);
        if (rank < need) {
            uint32_t slot = selTotal + rank;
            if (slot < K_SEL) st[WS_SEL + b * K_SEL + slot] = (uint32_t)i0;
            rv0 = (T != 0u) ? 1.0f : 0.0f;
        }
    }
    if (q1) {
        uint32_t rank = eqbase + preE1 + (uint32_t)__popcll(m1e & lt);
        if (rank < need) {
            uint32_t slot = selTotal + rank;
            if (slot < K_SEL) st[WS_SEL + b * K_SEL + slot] = (uint32_t)i1;
            rv1 = (T != 0u) ? 1.0f : 0.0f;
        }
    }
    refout[b * NQ + i0] = rv0;
    refout[b * NQ + i1] = rv1;
}

// ================= MFMA patch CNN: 2 waves / patch (R12 proven, unchanged) =================
__device__ __forceinline__ f16x8 ldfrag(const _Float16* wf, int frag, int l) {
    return *(const f16x8*)(wf + frag * 512 + l * 8);
}

template<bool XT>
__global__ __launch_bounds__(128) void patch_kernel(
    const float* __restrict__ hid, const float* __restrict__ pha,
    const _Float16* __restrict__ xt,
    const char* __restrict__ ws, float* __restrict__ out) {
    __shared__ _Float16 xs[64][40];      // [8x8 pos][ci], ci 0..31 valid
    __shared__ _Float16 y1n[36][40];     // [6x6 pos][oc], oc 0..23 valid, 24..39 zero
    __shared__ _Float16 pool[64][40];    // phaP [48][40] (conv1) then y2u [64][40] (conv3)
    __shared__ float pha8[64];
    __shared__ float biasL[56];
    float* y3s = (float*)&y1n[0][0];     // [36][16] f32 (dead after conv2)

    const _Float16* wf = (const _Float16*)ws;
    const float* biasG = (const float*)(ws + BIAS_OFF);
    const float* w4r   = (const float*)(ws + W4_OFF);
    const uint32_t* st = (const uint32_t*)(ws + ST_OFF);

    int tid = threadIdx.x, l = tid & 63, wid = tid >> 6;
    int lo = l & 15, hi = l >> 4;
    int bp = blockIdx.x;
    int b = (bp >= K_SEL) ? 1 : 0;
    int pi = bp - b * K_SEL;
    uint32_t idx = st[WS_SEL + b * K_SEL + pi] & 0x3FFFFu;   // clamp: fault-proof
    int hq = (int)(idx >> 9), wq = (int)(idx & 511u);

    if (tid < 53) biasL[tid] = biasG[tid];

    // ---- gather: lane = 8x8 position, wave = 16-channel half ----
    int ry = l >> 3, rx = l & 7;
    int hy = hq * 2 + ry - 3, hx = wq * 2 + rx - 3;
    bool inb = ((unsigned)hy < 1024u) && ((unsigned)hx < 1024u);
    float sy = fminf(fmaxf(hy * 0.5f - 0.25f, 0.f), 511.f);
    float sx = fminf(fmaxf(hx * 0.5f - 0.25f, 0.f), 511.f);
    int y0 = (int)sy, x0 = (int)sx;
    int y1c = min(y0 + 1, 511), x1c = min(x0 + 1, 511);
    float fy = sy - (float)y0, fx = sx - (float)x0;
    int o00 = y0 * 512 + x0, o01 = y0 * 512 + x1c, o10 = y1c * 512 + x0, o11 = y1c * 512 + x1c;
    float w00 = (1.f - fy) * (1.f - fx), w01 = (1.f - fy) * fx;
    float w10 = fy * (1.f - fx), w11 = fy * fx;

    _Float16 hv[16];
    if (XT) {
        if (inb) {
            const _Float16* xtb = xt + (size_t)b * NQ * 40 + (size_t)wid * 16;
            const _Float16* p00 = xtb + (size_t)o00 * 40;
            const _Float16* p01 = xtb + (size_t)o01 * 40;
            const _Float16* p10 = xtb + (size_t)o10 * 40;
            const _Float16* p11 = xtb + (size_t)o11 * 40;
            f16x8 a0 = *(const f16x8*)p00, a1 = *(const f16x8*)(p00 + 8);
            f16x8 b0 = *(const f16x8*)p01, b1 = *(const f16x8*)(p01 + 8);
            f16x8 c0 = *(const f16x8*)p10, c1 = *(const f16x8*)(p10 + 8);
            f16x8 d0 = *(const f16x8*)p11, d1 = *(const f16x8*)(p11 + 8);
#pragma unroll
            for (int j = 0; j < 8; j++) {
                hv[j]     = (_Float16)(w00 * (float)a0[j] + w01 * (float)b0[j]
                                     + w10 * (float)c0[j] + w11 * (float)d0[j]);
                hv[j + 8] = (_Float16)(w00 * (float)a1[j] + w01 * (float)b1[j]
                                     + w10 * (float)c1[j] + w11 * (float)d1[j]);
            }
        } else {
#pragma unroll
            for (int c = 0; c < 16; c++) hv[c] = (_Float16)0.f;
        }
    } else {
        const float* hb = hid + ((size_t)b * 32 + wid * 16) * NQ;
#pragma unroll
        for (int c = 0; c < 16; c++) {
            const float* p = hb + (size_t)c * NQ;
            float v = 0.f;
            if (inb) v = p[o00] * w00 + p[o01] * w01 + p[o10] * w10 + p[o11] * w11;
            hv[c] = (_Float16)v;
        }
    }
    f16x8 h0 = {hv[0], hv[1], hv[2], hv[3], hv[4], hv[5], hv[6], hv[7]};
    f16x8 h1 = {hv[8], hv[9], hv[10], hv[11], hv[12], hv[13], hv[14], hv[15]};
    {
        _Float16* xrow = &xs[l][wid * 16];
        *(f16x8*)xrow = h0;
        *((f16x8*)xrow + 1) = h1;
    }
    f16x8 z8 = {(_Float16)0.f, (_Float16)0.f, (_Float16)0.f, (_Float16)0.f,
                (_Float16)0.f, (_Float16)0.f, (_Float16)0.f, (_Float16)0.f};
    if (wid == 1) {
        const float* p = pha + (size_t)b * NQ;
        float v = 0.f;
        if (inb) v = p[o00] * w00 + p[o01] * w01 + p[o10] * w10 + p[o11] * w11;
        pha8[l] = v;
    }
    __syncthreads();

    // ---- phaP build (wave0, rows 0..47) + y1n pad-col zero (wave1) ----
    if (wid == 0) {
        if (l < 48) {
            int py = (l * 43) >> 8, px = l - py * 6;
            _Float16 tap[9];
#pragma unroll
            for (int t = 0; t < 9; t++) {
                int ky = t / 3, kx = t % 3;
                int ip = (py + ky) * 8 + px + kx;
                tap[t] = (_Float16)pha8[ip & 63];
            }
            _Float16* row = &pool[l][0];
            f16x8 r0 = {tap[0], tap[1], tap[2], tap[3], tap[4], tap[5], tap[6], tap[7]};
            f16x8 r1 = z8; r1[0] = tap[8];
            *(f16x8*)row = r0;
            *(f16x8*)(row + 8)  = r1;
            *(f16x8*)(row + 16) = z8;
            *(f16x8*)(row + 24) = z8;
        }
    } else {
        for (int i = l; i < 72; i += 64) {
            *(f16x8*)&y1n[i >> 1][24 + (i & 1) * 8] = z8;
        }
    }
    __syncthreads();

    // ---- conv1: 33ch -> 24, 8x8 -> 6x6, MFMA ----
    f32x4 zf = {0.f, 0.f, 0.f, 0.f};
    f32x4 aA0 = zf, aA1 = zf, aB = zf;
    int nA = wid * 16 + lo, nB = 32 + lo;
    int pyA = (nA * 43) >> 8, pxA = nA - pyA * 6;
    int pyB = (nB * 43) >> 8, pxB = nB - pyB * 6;
    {
        f16x8 A0 = ldfrag(wf, 36, l), A1 = ldfrag(wf, 37, l);
        f16x8 BA = *(const f16x8*)&pool[nA][hi * 8];
        f16x8 BB = *(const f16x8*)&pool[nB][hi * 8];
        aA0 = MFMA16(A0, BA, aA0);
        aA1 = MFMA16(A1, BA, aA1);
        aB  = MFMA16(wid ? A1 : A0, BB, aB);
    }
#pragma unroll
    for (int ky = 0; ky < 3; ky++) {
#pragma unroll
        for (int kt = 0; kt < 3; kt++) {
            f16x8 A0 = ldfrag(wf, ky * 6 + kt * 2 + 0, l);
            f16x8 A1 = ldfrag(wf, ky * 6 + kt * 2 + 1, l);
            int rA = ((pyA + ky) * 8 + pxA + kt) & 63;
            int rB = ((pyB + ky) * 8 + pxB + kt) & 63;
            f16x8 BA = *(const f16x8*)&xs[rA][hi * 8];
            f16x8 BB = *(const f16x8*)&xs[rB][hi * 8];
            aA0 = MFMA16(A0, BA, aA0);
            aA1 = MFMA16(A1, BA, aA1);
            aB  = MFMA16(wid ? A1 : A0, BB, aB);
        }
    }
    {
        f32x4 accs[3] = {aA0, aA1, aB};
        int mts[3] = {0, 1, wid};
        int nts[3] = {wid, wid, 2};
#pragma unroll
        for (int f = 0; f < 3; f++) {
            int n = nts[f] * 16 + lo;
            int ocb = mts[f] * 16 + hi * 4;
            if (n < 36 && ocb < 24) {
                f16x4 hh;
                hh[0] = (_Float16)fmaxf(accs[f][0] + biasL[ocb + 0], 0.f);
                hh[1] = (_Float16)fmaxf(accs[f][1] + biasL[ocb + 1], 0.f);
                hh[2] = (_Float16)fmaxf(accs[f][2] + biasL[ocb + 2], 0.f);
                hh[3] = (_Float16)fmaxf(accs[f][3] + biasL[ocb + 3], 0.f);
                *(f16x4*)&y1n[n][ocb] = hh;
            }
        }
    }
    __syncthreads();

    // ---- conv2 (wave0): 24ch 6x6 -> 16ch 4x4 ; wave1 zeroes y2u pads ----
    if (wid == 0) {
        f32x4 a2 = zf;
        int qy = lo >> 2, qx = lo & 3;
#pragma unroll
        for (int ky = 0; ky < 3; ky++) {
#pragma unroll
            for (int kt = 0; kt < 3; kt++) {
                f16x8 A = ldfrag(wf, 18 + ky * 3 + kt, l);
                int k = kt * 32 + hi * 8;
                const _Float16* bptr;
                if (k < 72) {
                    int kx = k / 24, ci0 = k - kx * 24;
                    bptr = &y1n[(qy + ky) * 6 + qx + kx][ci0];
                } else {
                    bptr = &y1n[0][24];
                }
                f16x8 B = *(const f16x8*)bptr;
                a2 = MFMA16(A, B, a2);
            }
        }
        int ocb = hi * 4;
        f16x4 hh;
        hh[0] = (_Float16)fmaxf(a2[0] + biasL[24 + ocb + 0], 0.f);
        hh[1] = (_Float16)fmaxf(a2[1] + biasL[24 + ocb + 1], 0.f);
        hh[2] = (_Float16)fmaxf(a2[2] + biasL[24 + ocb + 2], 0.f);
        hh[3] = (_Float16)fmaxf(a2[3] + biasL[24 + ocb + 3], 0.f);
#pragma unroll
        for (int dy = 0; dy < 2; dy++)
#pragma unroll
            for (int dx = 0; dx < 2; dx++) {
                int row = (2 * qy + dy) * 8 + 2 * qx + dx;
                *(f16x4*)&pool[row][ocb] = hh;
            }
    } else {
        *(f16x8*)&pool[l][16] = z8;
        *(f16x8*)&pool[l][24] = z8;
    }
    __syncthreads();

    // ---- conv3: 16ch 8x8 -> 12ch 6x6 ----
    f32x4 aC = zf, aD = zf;
    int nC = wid * 16 + lo, nD = 32 + lo;
    int pyC = (nC * 43) >> 8, pxC = nC - pyC * 6;
    int pyD = (nD * 43) >> 8, pxD = nD - pyD * 6;
#pragma unroll
    for (int s = 0; s < 9; s++) {
        int ky = s / 3, kx = s % 3;
        f16x8 A = ldfrag(wf, 27 + s, l);
        f16x8 BC = *(const f16x8*)&pool[((pyC + ky) * 8 + pxC + kx) & 63][hi * 8];
        aC = MFMA16(A, BC, aC);
        if (wid) {
            f16x8 BD = *(const f16x8*)&pool[((pyD + ky) * 8 + pxD + kx) & 63][hi * 8];
            aD = MFMA16(A, BD, aD);
        }
    }
    __syncthreads();
    {
        int ocb = hi * 4;
        f32x4 accs[2] = {aC, aD};
        int nts[2] = {wid, 2};
        int cnt = wid ? 2 : 1;
        for (int f = 0; f < cnt; f++) {
            int n = nts[f] * 16 + lo;
            if (n < 36) {
                f32x4 v;
#pragma unroll
                for (int r = 0; r < 4; r++) {
                    float bb = (ocb + r < 12) ? biasL[40 + ocb + r] : 0.f;
                    float x = accs[f][r] + bb;
                    v[r] = (ocb + r < 12) ? fmaxf(x, 0.f) : 0.f;
                }
                *(f32x4*)&y3s[n * 16 + ocb] = v;
            }
        }
    }
    __syncthreads();

    // ---- conv4 (wave0): 12ch 6x6 -> 1ch 4x4, f32, + scatter store ----
    if (wid == 0) {
        int r4 = lo >> 2, c4 = lo & 3, cig = hi;
        float acc = 0.f;
#pragma unroll
        for (int t = 0; t < 9; t++) {
            int ky = t / 3, kx = t % 3;
            const f32x4 xv = *(const f32x4*)&y3s[((r4 + ky) * 6 + c4 + kx) * 16 + cig * 4];
            const f32x4 wv = *(const f32x4*)(w4r + t * 16 + cig * 4);
            acc += xv[0] * wv[0] + xv[1] * wv[1] + xv[2] * wv[2] + xv[3] * wv[3];
        }
        acc += __shfl_xor(acc, 32);
        acc += __shfl_xor(acc, 16);
        if (l < 16) {
            out[(size_t)b * 4194304 + (size_t)(hq * 4 + r4) * 2048 + (wq * 4 + c4)] = acc + biasL[52];
        }
    }
}

extern "C" void kernel_launch(void* const* d_in, const int* in_sizes, int n_in,
                              void* d_out, int out_size, void* d_ws, size_t ws_size,
                              hipStream_t stream) {
    const float* pha = (const float*)d_in[0];
    const float* err = (const float*)d_in[1];
    const float* hid = (const float*)d_in[2];
    const float* w1  = (const float*)d_in[3];
    const float* g1  = (const float*)d_in[4];
    const float* bb1 = (const float*)d_in[5];
    const float* m1  = (const float*)d_in[6];
    const float* v1  = (const float*)d_in[7];
    const float* w2  = (const float*)d_in[8];
    const float* g2  = (const float*)d_in[9];
    const float* bb2 = (const float*)d_in[10];
    const float* m2  = (const float*)d_in[11];
    const float* v2  = (const float*)d_in[12];
    const float* w3  = (const float*)d_in[13];
    const float* g3  = (const float*)d_in[14];
    const float* bb3 = (const float*)d_in[15];
    const float* m3  = (const float*)d_in[16];
    const float* v3  = (const float*)d_in[17];
    const float* w4  = (const float*)d_in[18];
    const float* b4  = (const float*)d_in[19];

    float* out    = (float*)d_out;
    float* refout = out + (size_t)NB * 4194304;
    char* ws      = (char*)d_ws;
    uint32_t* st  = (uint32_t*)(ws + ST_OFF);
    _Float16* xt  = (_Float16*)(ws + XT_OFF);
    bool use_xt   = (ws_size >= WS_NEED);     // constant across calls -> deterministic

    hipMemsetAsync(st, 0, (WS_HIST + 4 * 512) * sizeof(uint32_t), stream);

    if (use_xt) {
        const int NTU = 10240, SLICE = 1707;
        int off = 0;
        int n = SLICE;
        l1_kernel<<<2112 + n, 256, 0, stream>>>(err, st, w1, g1, bb1, m1, v1,
                                                w2, g2, bb2, m2, v2, w3, g3, bb3, m3, v3,
                                                w4, b4, ws, hid, pha, xt, out, off);
        off += n;
        for (int r = 1; r < 4; r++) {
            n = (off + SLICE <= NTU) ? SLICE : (NTU - off);
            hist_kernel<<<2048 + n, 256, 0, stream>>>(err, st, r, hid, pha, xt, out, off);
            off += n;
        }
        n = (off + SLICE <= NTU) ? SLICE : (NTU - off);
        ccount_kernel<<<1024 + n, 256, 0, stream>>>(err, st, hid, pha, xt, out, off);
        off += n;
        n = NTU - off;
        cplace_kernel<<<1024 + n, 256, 0, stream>>>(err, st, refout, hid, pha, xt, out, off);
        patch_kernel<true><<<2 * K_SEL, 128, 0, stream>>>(hid, pha, xt, ws, out);
    } else {
        upsample_kernel<<<8192, 256, 0, stream>>>(pha, out);
        l1_kernel<<<2112, 256, 0, stream>>>(err, st, w1, g1, bb1, m1, v1,
                                            w2, g2, bb2, m2, v2, w3, g3, bb3, m3, v3,
                                            w4, b4, ws, hid, pha, xt, out, 0);
        for (int r = 1; r < 4; r++)
            hist_kernel<<<2048, 256, 0, stream>>>(err, st, r, hid, pha, xt, out, 0);
        ccount_kernel<<<1024, 256, 0, stream>>>(err, st, hid, pha, xt, out, 0);
        cplace_kernel<<<1024, 256, 0, stream>>>(err, st, refout, hid, pha, xt, out, 0);
        patch_kernel<false><<<2 * K_SEL, 128, 0, stream>>>(hid, pha, xt, ws, out);
    }
}